// Round 11
// baseline (604.674 us; speedup 1.0000x reference)
//
#include <hip/hip_runtime.h>
#include <stdint.h>
#include <stddef.h>

#define NN 8192      // nodes
#define KD 256       // in_dim
#define CD 256       // out_dim*heads
#define FD 128       // out_dim
#define BI 128       // i-tile rows per block (k_gat)
#define BJ 64        // j-tile
#define LOG2E 1.44269504f

typedef __attribute__((ext_vector_type(4))) float f32x4;
typedef __attribute__((ext_vector_type(2))) float f32x2;
typedef __attribute__((ext_vector_type(8))) short b16x8;

// pack two f32 -> two bf16 (RNE) in ONE instruction
__device__ __forceinline__ unsigned int cvtpk(float lo, float hi) {
    unsigned int r;
    asm("v_cvt_pk_bf16_f32 %0, %1, %2" : "=v"(r) : "v"(lo), "v"(hi));
    return r;
}

// raw 2^x (hardware transcendental); s_nop guards the trans-use window
__device__ __forceinline__ float exp2raw(float x) {
    float r;
    asm("v_exp_f32 %0, %1\n\ts_nop 0" : "=v"(r) : "v"(x));
    return r;
}

// async global->LDS, 16B per lane; lds dest = wave-uniform base + lane*16
__device__ __forceinline__ void async16(const void* g, void* l) {
    __builtin_amdgcn_global_load_lds(
        (const __attribute__((address_space(1))) unsigned int*)g,
        (__attribute__((address_space(3))) unsigned int*)l, 16, 0, 0);
}

// ---------------------------------------------------------------------------
// Kernel 1 (fused): blocks 0..255 = transform (head-major s,d, prescaled);
// blocks 256..2047 = adjacency bit-pack (BW-bound, runs CONCURRENTLY with the
// compute-bound transform blocks -> wall ~= max(pack, transform)).
// ---------------------------------------------------------------------------
__global__ __launch_bounds__(256) void k_fused(
    const float* __restrict__ feat, const float* __restrict__ W,
    const float* __restrict__ asrc, const float* __restrict__ adst,
    const int* __restrict__ adj,
    unsigned short* __restrict__ Tt, float* __restrict__ s, float* __restrict__ d,
    unsigned long long* __restrict__ bits)
{
    __shared__ unsigned short a_lds[32 * 32];    // 2KB
    __shared__ unsigned short b_lds[256 * 32];   // 16KB
    __shared__ unsigned short tr_lds[256 * 40];  // 20KB
    __shared__ float sc_lds[4][32];              // .5KB
    __shared__ float dc_lds[4][32];              // .5KB

    const int t = threadIdx.x;
    if (blockIdx.x >= 256) {
        // ---- bit-pack: adj[8192][8192] 0/1 int -> bits[8192][128] u64 ----
        const int lane = t & 63;
        const int gw = (blockIdx.x - 256) * 4 + (t >> 6);
        const int nwaves = (gridDim.x - 256) * 4;
        const int total = NN * (NN / 64);            // 1,048,576 words
        for (int idx = gw; idx < total; idx += nwaves) {
            const int row = idx >> 7, w64 = idx & 127;
            const int v = adj[(size_t)row * NN + w64 * 64 + lane];
            const unsigned long long m = __ballot(v != 0);
            if (lane == 0) bits[idx] = m;
        }
        return;
    }
    // ---- transform: 32-row block, grid slice 0..255 ----
    const int wave = t >> 6, lane = t & 63;
    const int l15 = lane & 15, quad = lane >> 4;
    const int n0 = blockIdx.x * 32;

    f32x4 acc[2][4] = {};
    for (int kc = 0; kc < 8; ++kc) {
        const int k0 = kc * 32;
        __syncthreads();
        if (t < 128) { // stage A: features[n0+ai][k0 + ag*8 .. +7] -> bf16
            const int ai = t >> 2, ag = t & 3;
            const float* src = feat + (size_t)(n0 + ai) * KD + k0 + ag * 8;
            const float4 v0 = *(const float4*)src;
            const float4 v1 = *(const float4*)(src + 4);
            union { unsigned int u[4]; b16x8 v; } pk;
            pk.u[0] = cvtpk(v0.x, v0.y); pk.u[1] = cvtpk(v0.z, v0.w);
            pk.u[2] = cvtpk(v1.x, v1.y); pk.u[3] = cvtpk(v1.z, v1.w);
            const int slot = ag ^ ((ai >> 1) & 3);
            *(b16x8*)&a_lds[ai * 32 + slot * 8] = pk.v;
        }
        for (int p = 0; p < 4; ++p) { // stage B: W[c][k0 + g*8 .. +7]
            const int G = p * 256 + t;
            const int c = G >> 2, g = G & 3;
            const float* src = W + (size_t)c * KD + k0 + g * 8;
            const float4 v0 = *(const float4*)src;
            const float4 v1 = *(const float4*)(src + 4);
            union { unsigned int u[4]; b16x8 v; } pk;
            pk.u[0] = cvtpk(v0.x, v0.y); pk.u[1] = cvtpk(v0.z, v0.w);
            pk.u[2] = cvtpk(v1.x, v1.y); pk.u[3] = cvtpk(v1.z, v1.w);
            const int slot = g ^ ((c >> 1) & 3);
            *(b16x8*)&b_lds[c * 32 + slot * 8] = pk.v;
        }
        __syncthreads();
        b16x8 af[2], bfr[4];
        for (int mt = 0; mt < 2; ++mt) {
            const int m = mt * 16 + l15;
            af[mt] = *(const b16x8*)&a_lds[m * 32 + (quad ^ ((m >> 1) & 3)) * 8];
        }
        for (int nt = 0; nt < 4; ++nt) {
            const int c = wave * 64 + nt * 16 + l15;
            bfr[nt] = *(const b16x8*)&b_lds[c * 32 + (quad ^ ((c >> 1) & 3)) * 8];
        }
        for (int mt = 0; mt < 2; ++mt)
            for (int nt = 0; nt < 4; ++nt)
                acc[mt][nt] = __builtin_amdgcn_mfma_f32_16x16x32_bf16(
                    af[mt], bfr[nt], acc[mt][nt], 0, 0, 0);
    }

    // ---- epilogue: scores (fp32) + transposed bf16 store ----
    float aS[4], aD[4];
    for (int nt = 0; nt < 4; ++nt) {
        const int c = wave * 64 + nt * 16 + l15;
        aS[nt] = asrc[c]; aD[nt] = adst[c];
    }
    for (int mt = 0; mt < 2; ++mt)
        for (int r = 0; r < 4; ++r) {
            float vs = 0.f, vd = 0.f;
            for (int nt = 0; nt < 4; ++nt) {
                const float x = acc[mt][nt][r];
                vs += x * aS[nt]; vd += x * aD[nt];
            }
            vs += __shfl_xor(vs, 1); vd += __shfl_xor(vd, 1);
            vs += __shfl_xor(vs, 2); vd += __shfl_xor(vd, 2);
            vs += __shfl_xor(vs, 4); vd += __shfl_xor(vd, 4);
            vs += __shfl_xor(vs, 8); vd += __shfl_xor(vd, 8);
            if (l15 == 0) {
                const int nl = mt * 16 + quad * 4 + r;
                sc_lds[wave][nl] = vs; dc_lds[wave][nl] = vd;
            }
        }
    for (int mt = 0; mt < 2; ++mt)
        for (int nt = 0; nt < 4; ++nt) {
            const int c = wave * 64 + nt * 16 + l15;
            const int n = mt * 16 + quad * 4;           // r-pairs (n..n+3)
            *(unsigned int*)&tr_lds[c * 40 + n] =
                cvtpk(acc[mt][nt][0], acc[mt][nt][1]);
            *(unsigned int*)&tr_lds[c * 40 + n + 2] =
                cvtpk(acc[mt][nt][2], acc[mt][nt][3]);
        }
    __syncthreads();
    if (t < 64) {
        const int n = t >> 1, h = t & 1;
        // HEAD-MAJOR + PRE-SCALED by log2e for k_gat's raw v_exp_f32 path
        s[(size_t)h * NN + n0 + n] = (sc_lds[h * 2][n] + sc_lds[h * 2 + 1][n]) * LOG2E;
        d[(size_t)h * NN + n0 + n] = (dc_lds[h * 2][n] + dc_lds[h * 2 + 1][n]) * LOG2E;
    }
    for (int p = 0; p < 4; ++p) {
        const int idx = p * 256 + t;       // 1024 granules (256 c x 4)
        const int c = idx >> 2, g = idx & 3;
        *(b16x8*)(Tt + (size_t)c * NN + n0 + g * 8) = *(const b16x8*)&tr_lds[c * 40 + g * 8];
    }
}

// ---------------------------------------------------------------------------
// Kernel 2 (v11): BI=128, IN-REGISTER A-fragments (no w_lds!).
//   wave = (rh 0..7, head): lane(l15,quad) computes its OWN A-frag elements
//   exp(s[row=rh*16+l15] + d[j=ks*32+quad*8+e])*mask -- zero duplication,
//   the w_lds transpose round-trip + its 32KB vanish.
//   LDS = tt dbuf only = 64KB -> 2 blocks/CU; jsplit=8 -> grid (64,8)=512
//   = exactly 2/CU; bodies 8192, 32/CU with 2-way block overlap.
//   Mask from bitmask (1 u64/lane/body, L2-resident).  VMEM order per body:
//   bits+d (current, OLDEST) then stage DMA (next, newest) -> exp's operand
//   waits retire only the old ops; explicit vmcnt(2) keeps the 2 next-tile
//   DMAs in flight across the barrier and MFMA.
// ---------------------------------------------------------------------------
__global__ __launch_bounds__(1024, 8) void k_gat(
    const unsigned long long* __restrict__ bits, const unsigned short* __restrict__ Tt,
    const float* __restrict__ s, const float* __restrict__ d,
    float* __restrict__ num_part,   // [jsplit][NN][CD]
    float* __restrict__ den_part,   // [jsplit][2][NN]
    int jchunk)
{
    __shared__ unsigned short tt_lds[2][CD * BJ];    // 2 x 32KB, XOR-swizzled

    const int t = threadIdx.x;
    const int w = t >> 6, lane = t & 63;             // w: 0..15
    const int l15 = lane & 15, quad = lane >> 4;
    const int rh = w & 7;           // row-group: rows rh*16..+15
    const int h  = w >> 3;          // head
    const int i0 = blockIdx.x * BI;
    const int chunk = blockIdx.y;
    const int jbase = chunk * jchunk;
    const int irow = i0 + rh * 16 + l15;             // this lane's A-row
    const float sr = s[(size_t)h * NN + irow];       // pre-scaled by log2e
    const int njt = jchunk / BJ;                     // 16 (jsplit=8)

    f32x4 acc[8] = {};
    float den = 0.f;

    // ---- hoisted addresses (all loop-invariant) ----
    // DMA granule G=(p*16+w)*64+lane -> c = p*128 + c0; (c&7)=lane>>3, p-indep
    const int c0 = w * 8 + (lane >> 3);
    const int g0 = (lane & 7) ^ (c0 & 7);
    const unsigned short* tsrc0 = Tt + (size_t)c0 * NN + g0 * 8;
    const int toff0 = w * 1024;                      // + p*16384 bytes
    const unsigned long long* brow = bits + (size_t)irow * (NN >> 6);
    const int wb = jbase >> 6;
    const float* drow = d + (size_t)h * NN + quad * 8;
    const int bfb = (h * 128 + l15) * BJ;            // + nt*1024 + X[ks]
    const int X[2] = {((0 * 4 + quad) ^ (l15 & 7)) << 3,
                      ((1 * 4 + quad) ^ (l15 & 7)) << 3};

    // ---- prologue: DMA tile0 -> buf0 ----
    #pragma unroll
    for (int p = 0; p < 2; ++p)
        async16(tsrc0 + (size_t)p * 128 * NN + jbase,
                (char*)&tt_lds[0][0] + toff0 + p * 16384);

    int buf = 0;
    for (int jt = 0; jt < njt; ++jt) {
        const int j0 = jbase + jt * BJ;
        __builtin_amdgcn_s_barrier();   // prev MFMA done reading tt[buf^1]
        // current-tile operands FIRST (oldest in VMEM FIFO): bits + d
        const unsigned long long cb = brow[wb + jt];
        const float4 dv0 = *(const float4*)(drow + j0);
        const float4 dv1 = *(const float4*)(drow + j0 + 4);
        const float4 dv2 = *(const float4*)(drow + j0 + 32);
        const float4 dv3 = *(const float4*)(drow + j0 + 36);
        // stage NEXT tile (newest -- stays in flight through exp + MFMA)
        const int jn = (jt + 1 < njt) ? j0 + BJ : j0;
        #pragma unroll
        for (int p = 0; p < 2; ++p)
            async16(tsrc0 + (size_t)p * 128 * NN + jn,
                    (char*)&tt_lds[buf ^ 1][0] + toff0 + p * 16384);
        // exp -> in-register A fragments (lane owns row l15, k-slots quad*8+e)
        const unsigned int by0 = (unsigned int)(cb >> (quad * 8)) & 0xffu;
        const unsigned int by1 = (unsigned int)(cb >> (32 + quad * 8)) & 0xffu;
        union { unsigned int u[4]; b16x8 v; } pa0, pa1;
        {
            const float dj[8] = {dv0.x, dv0.y, dv0.z, dv0.w, dv1.x, dv1.y, dv1.z, dv1.w};
            float ef[8];
            #pragma unroll
            for (int e = 0; e < 8; ++e) {
                float x = sr + dj[e]; x = fmaxf(x, 0.2f * x);
                ef[e] = ((by0 >> e) & 1u) ? exp2raw(x) : 0.f;
                den += ef[e];
            }
            #pragma unroll
            for (int q = 0; q < 4; ++q) pa0.u[q] = cvtpk(ef[2 * q], ef[2 * q + 1]);
        }
        {
            const float dj[8] = {dv2.x, dv2.y, dv2.z, dv2.w, dv3.x, dv3.y, dv3.z, dv3.w};
            float ef[8];
            #pragma unroll
            for (int e = 0; e < 8; ++e) {
                float x = sr + dj[e]; x = fmaxf(x, 0.2f * x);
                ef[e] = ((by1 >> e) & 1u) ? exp2raw(x) : 0.f;
                den += ef[e];
            }
            #pragma unroll
            for (int q = 0; q < 4; ++q) pa1.u[q] = cvtpk(ef[2 * q], ef[2 * q + 1]);
        }
        // COUNTED wait: only the 2 next-tile DMAs may remain outstanding;
        // this body's bits/d (older) already retired by exp's waits, which
        // also certifies THIS tile's DMAs (issued last body, older still).
        asm volatile("s_waitcnt vmcnt(2)" ::: "memory");
        __builtin_amdgcn_s_barrier();
        __builtin_amdgcn_sched_barrier(0);
        // --- MFMA: num[rows rh*16.., head h cols] += pa @ T ---
        __builtin_amdgcn_s_setprio(1);
        #pragma unroll
        for (int nt = 0; nt < 8; ++nt) {
            const b16x8 bf = *(const b16x8*)&tt_lds[buf][bfb + nt * 1024 + X[0]];
            acc[nt] = __builtin_amdgcn_mfma_f32_16x16x32_bf16(pa0.v, bf, acc[nt], 0, 0, 0);
        }
        #pragma unroll
        for (int nt = 0; nt < 8; ++nt) {
            const b16x8 bf = *(const b16x8*)&tt_lds[buf][bfb + nt * 1024 + X[1]];
            acc[nt] = __builtin_amdgcn_mfma_f32_16x16x32_bf16(pa1.v, bf, acc[nt], 0, 0, 0);
        }
        __builtin_amdgcn_s_setprio(0);
        buf ^= 1;
    }
    // drain tail DMAs before the wave retires / LDS is reallocated
    asm volatile("s_waitcnt vmcnt(0)" ::: "memory");
    // den: lane holds its row's partial over its 16 k-slots; sum across quads
    den += __shfl_xor(den, 16);
    den += __shfl_xor(den, 32);
    if (quad == 0)
        den_part[((size_t)chunk * 2 + h) * NN + irow] = den;
    // num: acc[nt][r] -> n = i0 + rh*16 + quad*4 + r, c = h*128 + nt*16 + l15
    float* np_ = num_part + (size_t)chunk * NN * CD;
    for (int nt = 0; nt < 8; ++nt)
        for (int r = 0; r < 4; ++r) {
            const int n = i0 + rh * 16 + quad * 4 + r;
            const int c = h * 128 + nt * 16 + l15;
            np_[(size_t)n * CD + c] = acc[nt][r];
        }
}

// ---------------------------------------------------------------------------
// Kernel 3: combine partials, normalize, mean over heads.  grid=4096
// ---------------------------------------------------------------------------
__global__ __launch_bounds__(256) void k_combine(
    const float* __restrict__ num_part, const float* __restrict__ den_part,
    float* __restrict__ out, int jsplit)
{
    const int idx = blockIdx.x * 256 + threadIdx.x;   // NN*FD
    const int n = idx >> 7, f = idx & 127;
    const size_t row = (size_t)n * CD;
    float n0 = 0.f, n1 = 0.f, d0 = 0.f, d1 = 0.f;
    for (int c = 0; c < jsplit; ++c) {
        const size_t base = (size_t)c * NN * CD;
        n0 += num_part[base + row + f];
        n1 += num_part[base + row + 128 + f];
        d0 += den_part[((size_t)c * 2 + 0) * NN + n];
        d1 += den_part[((size_t)c * 2 + 1) * NN + n];
    }
    const float r0 = d0 != 0.f ? n0 / d0 : 0.f;
    const float r1 = d1 != 0.f ? n1 / d1 : 0.f;
    out[idx] = 0.5f * (r0 + r1);
}

// ---------------------------------------------------------------------------
extern "C" void kernel_launch(void* const* d_in, const int* in_sizes, int n_in,
                              void* d_out, int out_size, void* d_ws, size_t ws_size,
                              hipStream_t stream) {
    const float* feat = (const float*)d_in[0];
    const int*   adj  = (const int*)d_in[1];
    const float* W    = (const float*)d_in[2];
    const float* asrc = (const float*)d_in[3];
    const float* adst = (const float*)d_in[4];
    float* out = (float*)d_out;

    // jsplit=8 -> grid (64,8)=512 = exactly 2 blocks/CU for the 64KB k_gat.
    // Needs 8MB(Tt/s/d/den) + 64MB(nump) + 8MB(bits) = 80MB; the harness fill
    // poisons exactly 1 GiB of ws, so ws_size >= 1 GiB.  jsplit=4 fallback.
    const int jsplit = (ws_size >= ((size_t)81 << 20)) ? 8 : 4;
    const int jchunk = NN / jsplit;

    char* ws = (char*)d_ws;
    unsigned short* Tt = (unsigned short*)ws;                       // 4 MB
    float* s    = (float*)(ws + ((size_t)4 << 20));                 // 64 KB
    float* dsc  = (float*)(ws + ((size_t)4 << 20) + (64 << 10));    // 64 KB
    float* den  = (float*)(ws + ((size_t)4 << 20) + (128 << 10));   // <=512 KB
    float* nump = (float*)(ws + ((size_t)8 << 20));                 // jsplit*8 MB
    unsigned long long* bits = (unsigned long long*)
        (ws + ((size_t)(8 + 8 * (size_t)jsplit) << 20));            // 8 MB

    k_fused<<<2048, 256, 0, stream>>>(feat, W, asrc, adst, adj, Tt, s, dsc, bits);
    k_gat<<<dim3(NN / BI, jsplit), 1024, 0, stream>>>(bits, Tt, s, dsc, nump, den, jchunk);
    k_combine<<<NN * FD / 256, 256, 0, stream>>>(nump, den, out, jsplit);
}

// Round 12
// 419.606 us; speedup vs baseline: 1.4411x; 1.4411x over previous
//
#include <hip/hip_runtime.h>
#include <stdint.h>
#include <stddef.h>

#define NN 8192      // nodes
#define KD 256       // in_dim
#define CD 256       // out_dim*heads
#define FD 128       // out_dim
#define BI 128       // i-tile rows per block (k_gat)
#define BJ 64        // j-tile
#define LOG2E 1.44269504f

typedef __attribute__((ext_vector_type(4))) float f32x4;
typedef __attribute__((ext_vector_type(2))) float f32x2;
typedef __attribute__((ext_vector_type(8))) short b16x8;

// pack two f32 -> two bf16 (RNE) in ONE instruction
__device__ __forceinline__ unsigned int cvtpk(float lo, float hi) {
    unsigned int r;
    asm("v_cvt_pk_bf16_f32 %0, %1, %2" : "=v"(r) : "v"(lo), "v"(hi));
    return r;
}

// raw 2^x (hardware transcendental); s_nop guards the trans-use window
__device__ __forceinline__ float exp2raw(float x) {
    float r;
    asm("v_exp_f32 %0, %1\n\ts_nop 0" : "=v"(r) : "v"(x));
    return r;
}

// async global->LDS, 16B per lane; lds dest = wave-uniform base + lane*16
__device__ __forceinline__ void async16(const void* g, void* l) {
    __builtin_amdgcn_global_load_lds(
        (const __attribute__((address_space(1))) unsigned int*)g,
        (__attribute__((address_space(3))) unsigned int*)l, 16, 0, 0);
}

// ---------------------------------------------------------------------------
// Kernel 1 (v7): 32-row blocks, grid=256 (all CUs).  Stores s,d interleaved
// [n][2], PRE-SCALED by log2(e).  Session-best version, verbatim.
// ---------------------------------------------------------------------------
__global__ __launch_bounds__(256) void k_transform(
    const float* __restrict__ feat, const float* __restrict__ W,
    const float* __restrict__ asrc, const float* __restrict__ adst,
    unsigned short* __restrict__ Tt, float* __restrict__ s, float* __restrict__ d)
{
    __shared__ unsigned short a_lds[32 * 32];    // 2KB
    __shared__ unsigned short b_lds[256 * 32];   // 16KB
    __shared__ unsigned short tr_lds[256 * 40];  // 20KB (stride 40 = 80B, 16B-aligned)
    __shared__ float sc_lds[4][32];              // .5KB
    __shared__ float dc_lds[4][32];              // .5KB

    const int t = threadIdx.x;
    const int wave = t >> 6, lane = t & 63;
    const int l15 = lane & 15, quad = lane >> 4;
    const int n0 = blockIdx.x * 32;

    f32x4 acc[2][4] = {};
    for (int kc = 0; kc < 8; ++kc) {
        const int k0 = kc * 32;
        __syncthreads();
        if (t < 128) { // stage A: features[n0+ai][k0 + ag*8 .. +7] -> bf16
            const int ai = t >> 2, ag = t & 3;
            const float* src = feat + (size_t)(n0 + ai) * KD + k0 + ag * 8;
            const float4 v0 = *(const float4*)src;
            const float4 v1 = *(const float4*)(src + 4);
            union { unsigned int u[4]; b16x8 v; } pk;
            pk.u[0] = cvtpk(v0.x, v0.y); pk.u[1] = cvtpk(v0.z, v0.w);
            pk.u[2] = cvtpk(v1.x, v1.y); pk.u[3] = cvtpk(v1.z, v1.w);
            const int slot = ag ^ ((ai >> 1) & 3);
            *(b16x8*)&a_lds[ai * 32 + slot * 8] = pk.v;
        }
        for (int p = 0; p < 4; ++p) { // stage B: W[c][k0 + g*8 .. +7]
            const int G = p * 256 + t;
            const int c = G >> 2, g = G & 3;
            const float* src = W + (size_t)c * KD + k0 + g * 8;
            const float4 v0 = *(const float4*)src;
            const float4 v1 = *(const float4*)(src + 4);
            union { unsigned int u[4]; b16x8 v; } pk;
            pk.u[0] = cvtpk(v0.x, v0.y); pk.u[1] = cvtpk(v0.z, v0.w);
            pk.u[2] = cvtpk(v1.x, v1.y); pk.u[3] = cvtpk(v1.z, v1.w);
            const int slot = g ^ ((c >> 1) & 3);
            *(b16x8*)&b_lds[c * 32 + slot * 8] = pk.v;
        }
        __syncthreads();
        b16x8 af[2], bfr[4];
        for (int mt = 0; mt < 2; ++mt) {
            const int m = mt * 16 + l15;
            af[mt] = *(const b16x8*)&a_lds[m * 32 + (quad ^ ((m >> 1) & 3)) * 8];
        }
        for (int nt = 0; nt < 4; ++nt) {
            const int c = wave * 64 + nt * 16 + l15;
            bfr[nt] = *(const b16x8*)&b_lds[c * 32 + (quad ^ ((c >> 1) & 3)) * 8];
        }
        for (int mt = 0; mt < 2; ++mt)
            for (int nt = 0; nt < 4; ++nt)
                acc[mt][nt] = __builtin_amdgcn_mfma_f32_16x16x32_bf16(
                    af[mt], bfr[nt], acc[mt][nt], 0, 0, 0);
    }

    // ---- epilogue: scores (fp32) + transposed bf16 store ----
    float aS[4], aD[4];
    for (int nt = 0; nt < 4; ++nt) {
        const int c = wave * 64 + nt * 16 + l15;
        aS[nt] = asrc[c]; aD[nt] = adst[c];
    }
    for (int mt = 0; mt < 2; ++mt)
        for (int r = 0; r < 4; ++r) {
            float vs = 0.f, vd = 0.f;
            for (int nt = 0; nt < 4; ++nt) {
                const float x = acc[mt][nt][r];
                vs += x * aS[nt]; vd += x * aD[nt];
            }
            vs += __shfl_xor(vs, 1); vd += __shfl_xor(vd, 1);
            vs += __shfl_xor(vs, 2); vd += __shfl_xor(vd, 2);
            vs += __shfl_xor(vs, 4); vd += __shfl_xor(vd, 4);
            vs += __shfl_xor(vs, 8); vd += __shfl_xor(vd, 8);
            if (l15 == 0) {
                const int nl = mt * 16 + quad * 4 + r;
                sc_lds[wave][nl] = vs; dc_lds[wave][nl] = vd;
            }
        }
    for (int mt = 0; mt < 2; ++mt)
        for (int nt = 0; nt < 4; ++nt) {
            const int c = wave * 64 + nt * 16 + l15;
            const int n = mt * 16 + quad * 4;           // r-pairs (n..n+3)
            *(unsigned int*)&tr_lds[c * 40 + n] =
                cvtpk(acc[mt][nt][0], acc[mt][nt][1]);
            *(unsigned int*)&tr_lds[c * 40 + n + 2] =
                cvtpk(acc[mt][nt][2], acc[mt][nt][3]);
        }
    __syncthreads();
    if (t < 64) {
        const int n = t >> 1, h = t & 1;
        // PRE-SCALED by log2e for k_gat's raw v_exp_f32 path
        s[(size_t)(n0 + n) * 2 + h] = (sc_lds[h * 2][n] + sc_lds[h * 2 + 1][n]) * LOG2E;
        d[(size_t)(n0 + n) * 2 + h] = (dc_lds[h * 2][n] + dc_lds[h * 2 + 1][n]) * LOG2E;
    }
    for (int p = 0; p < 4; ++p) {
        const int idx = p * 256 + t;       // 1024 granules (256 c x 4)
        const int c = idx >> 2, g = idx & 3;
        *(b16x8*)(Tt + (size_t)c * NN + n0 + g * 8) = *(const b16x8*)&tr_lds[c * 40 + g * 8];
    }
}

// ---------------------------------------------------------------------------
// Kernel 2 (v10, session best): BI=128 body-halving.  1024 thr / 16 waves
//   (4 row-groups x 4 col-quarters), grid (64,4) = 256 blocks = 1 block/CU.
//   Bodies: 8192.  LDS = tt dbuf 64KB + w 32KB = 96KB.  VMEM/body = 2 DMA +
//   2 adj + 4 d = 8 -> counted vmcnt(8).  Proven pipeline: raw barriers,
//   ping-pong reg sets, XOR swizzles both sides, setprio, prescaled s/d.
// ---------------------------------------------------------------------------
__global__ __launch_bounds__(1024, 4) void k_gat(
    const int* __restrict__ adj, const unsigned short* __restrict__ Tt,
    const float* __restrict__ s, const float* __restrict__ d,
    float* __restrict__ num_part,   // [jsplit][NN][CD]
    float* __restrict__ den_part,   // [jsplit][2][NN]
    int jchunk)
{
    __shared__ unsigned short tt_lds[2][CD * BJ];    // 2 x 32KB
    __shared__ unsigned short w_lds[2 * BI * BJ];    // 32KB (2 heads), XOR-swizzled

    const int t = threadIdx.x;
    const int w = t >> 6, lane = t & 63;             // w: 0..15
    const int l15 = lane & 15, quad = lane >> 4;
    const int rh = w & 3;           // row-group (0..3): rows rh*32..+31
    const int cq = w >> 2;          // col-quarter (0..3) across CD
    const int h  = cq >> 1;         // head
    const int fh = cq & 1;          // f-half
    const int i0 = blockIdx.x * BI;
    const int chunk = blockIdx.y;
    const int jbase = chunk * jchunk;

    const int wi = t >> 3;          // 0..127 : row within i-tile
    const int j8 = t & 7;           // 0..7   : 8-wide j granule
    const int gi = i0 + wi;
    const f32x2 s01 = *(const f32x2*)(s + (size_t)gi * 2);   // pre-scaled
    const int cbase = h * 128 + fh * 64;

    f32x4 acc[2][4] = {};
    float den0 = 0.f, den1 = 0.f;
    const int njt = jchunk / BJ;    // 32 (jsplit=4) -- even

    // ---- hoisted addresses (all loop-invariant) ----
    const int* arow = adj + (size_t)gi * NN + j8 * 8;
    const float* drow = d + (size_t)j8 * 16;              // + 2*j at use
    // DMA granule G=(p*16+w)*64+lane -> c = p*128 + c0; (c&7)=lane>>3, p-indep
    const int c0 = w * 8 + (lane >> 3);
    const int g0 = (lane & 7) ^ (c0 & 7);
    const unsigned short* tsrc0 = Tt + (size_t)c0 * NN + g0 * 8;
    const int toff0 = w * 1024;                           // + p*16384 bytes
    const int slot = (j8 ^ (wi & 7)) << 3;
    unsigned short* wp0 = &w_lds[(0 * BI + wi) * BJ + slot];
    const int m0 = rh * 32 + l15;
    const int afb = (h * BI + m0) * BJ;                   // + mt*1024
    const int bfb = (cbase + l15) * BJ;                   // + nt*1024
    const int X[2] = {((0 * 4 + quad) ^ (l15 & 7)) << 3,
                      ((1 * 4 + quad) ^ (l15 & 7)) << 3};

    // ---- prologue: DMA tile0 -> buf0; prefetch adj/d(tile0) into A regs ----
    #pragma unroll
    for (int p = 0; p < 2; ++p)
        async16(tsrc0 + (size_t)p * 128 * NN + jbase,
                (char*)&tt_lds[0][0] + toff0 + p * 16384);
    int4 aA0 = *(const int4*)(arow + jbase);
    int4 aA1 = *(const int4*)(arow + jbase + 4);
    const float4* dpp = (const float4*)(drow + 2 * jbase);
    float4 dA0 = dpp[0], dA1 = dpp[1], dA2 = dpp[2], dA3 = dpp[3];
    int4 aB0, aB1; float4 dB0, dB1, dB2, dB3;

    auto body = [&](int jt, int buf,
                    int4& ca0, int4& ca1, float4& cd0, float4& cd1, float4& cd2, float4& cd3,
                    int4& na0, int4& na1, float4& nd0, float4& nd1, float4& nd2, float4& nd3) {
        const int j0 = jbase + jt * BJ;
        // all waves finished MFMA(jt-1) -> its tt buffer + w_lds are free
        __builtin_amdgcn_s_barrier();
        // stage NEXT tile into the released buffer
        const int jn = (jt + 1 < njt) ? j0 + BJ : j0;
        #pragma unroll
        for (int p = 0; p < 2; ++p)
            async16(tsrc0 + (size_t)p * 128 * NN + jn,
                    (char*)&tt_lds[buf ^ 1][0] + toff0 + p * 16384);
        // prefetch next adj + d into the OTHER reg set (full iter of slack)
        na0 = *(const int4*)(arow + jn);
        na1 = *(const int4*)(arow + jn + 4);
        { const float4* dnp = (const float4*)(drow + 2 * jn);
          nd0 = dnp[0]; nd1 = dnp[1]; nd2 = dnp[2]; nd3 = dnp[3]; }
        // exp weights for CURRENT tile, head-pairs as f32x2
        union { float4 v[4]; f32x2 p[8]; } dv;
        dv.v[0] = cd0; dv.v[1] = cd1; dv.v[2] = cd2; dv.v[3] = cd3;
        const int am[8] = {ca0.x, ca0.y, ca0.z, ca0.w, ca1.x, ca1.y, ca1.z, ca1.w};
        f32x2 ef[8];
        f32x2 dp = {0.f, 0.f};
        #pragma unroll
        for (int e = 0; e < 8; ++e) {
            const f32x2 x = s01 + dv.p[e];
            const f32x2 xm = __builtin_elementwise_max(x, 0.2f * x);
            const float r0 = exp2raw(xm.x), r1 = exp2raw(xm.y);
            const f32x2 em = {am[e] != 0 ? r0 : 0.f, am[e] != 0 ? r1 : 0.f};
            ef[e] = em; dp += em;
        }
        den0 += dp.x; den1 += dp.y;
        union { unsigned int u[4]; b16x8 v; } w0, w1;
        #pragma unroll
        for (int q = 0; q < 4; ++q) {
            w0.u[q] = cvtpk(ef[2 * q].x, ef[2 * q + 1].x);
            w1.u[q] = cvtpk(ef[2 * q].y, ef[2 * q + 1].y);
        }
        *(b16x8*)wp0 = w0.v;
        *(b16x8*)(wp0 + BI * BJ) = w1.v;
        // COUNTED wait: 8 newer VMEM (2 DMA + 2 adj + 4 d, all for jt+1)
        // -> tile jt's DMAs certified landed; jt+1's stay in flight.
        asm volatile("s_waitcnt vmcnt(8) lgkmcnt(0)" ::: "memory");
        __builtin_amdgcn_s_barrier();
        __builtin_amdgcn_sched_barrier(0);
        // --- MFMA: num[i0+rh*32.., cbase..cbase+63] += w_h @ T ---
        __builtin_amdgcn_s_setprio(1);
        #pragma unroll
        for (int ks = 0; ks < 2; ++ks) {
            b16x8 af[2], bf[4];
            #pragma unroll
            for (int mt = 0; mt < 2; ++mt)
                af[mt] = *(const b16x8*)&w_lds[afb + mt * 1024 + X[ks]];
            #pragma unroll
            for (int nt = 0; nt < 4; ++nt)
                bf[nt] = *(const b16x8*)&tt_lds[buf][bfb + nt * 1024 + X[ks]];
            #pragma unroll
            for (int mt = 0; mt < 2; ++mt)
                #pragma unroll
                for (int nt = 0; nt < 4; ++nt)
                    acc[mt][nt] = __builtin_amdgcn_mfma_f32_16x16x32_bf16(
                        af[mt], bf[nt], acc[mt][nt], 0, 0, 0);
        }
        __builtin_amdgcn_s_setprio(0);
    };

    for (int jt = 0; jt < njt; jt += 2) {
        body(jt,     0, aA0, aA1, dA0, dA1, dA2, dA3, aB0, aB1, dB0, dB1, dB2, dB3);
        body(jt + 1, 1, aB0, aB1, dB0, dB1, dB2, dB3, aA0, aA1, dA0, dA1, dA2, dA3);
    }
    // drain tail DMAs before the wave retires / LDS is reallocated
    asm volatile("s_waitcnt vmcnt(0)" ::: "memory");
    // reduce den over the 8 j8-lanes (lane bits 0..2)
    den0 += __shfl_xor(den0, 1); den0 += __shfl_xor(den0, 2); den0 += __shfl_xor(den0, 4);
    den1 += __shfl_xor(den1, 1); den1 += __shfl_xor(den1, 2); den1 += __shfl_xor(den1, 4);
    if (j8 == 0) {
        den_part[((size_t)chunk * 2 + 0) * NN + gi] = den0;
        den_part[((size_t)chunk * 2 + 1) * NN + gi] = den1;
    }
    float* np_ = num_part + (size_t)chunk * NN * CD;
    for (int mt = 0; mt < 2; ++mt)
        for (int nt = 0; nt < 4; ++nt)
            for (int r = 0; r < 4; ++r) {
                const int n = i0 + rh * 32 + mt * 16 + quad * 4 + r;
                const int c = cbase + nt * 16 + l15;
                np_[(size_t)n * CD + c] = acc[mt][nt][r];
            }
}

// ---------------------------------------------------------------------------
// Kernel 3: combine partials, normalize, mean over heads.  grid=4096
// ---------------------------------------------------------------------------
__global__ __launch_bounds__(256) void k_combine(
    const float* __restrict__ num_part, const float* __restrict__ den_part,
    float* __restrict__ out, int jsplit)
{
    const int idx = blockIdx.x * 256 + threadIdx.x;   // NN*FD
    const int n = idx >> 7, f = idx & 127;
    const size_t row = (size_t)n * CD;
    float n0 = 0.f, n1 = 0.f, d0 = 0.f, d1 = 0.f;
    for (int c = 0; c < jsplit; ++c) {
        const size_t base = (size_t)c * NN * CD;
        n0 += num_part[base + row + f];
        n1 += num_part[base + row + 128 + f];
        d0 += den_part[((size_t)c * 2 + 0) * NN + n];
        d1 += den_part[((size_t)c * 2 + 1) * NN + n];
    }
    const float r0 = d0 != 0.f ? n0 / d0 : 0.f;
    const float r1 = d1 != 0.f ? n1 / d1 : 0.f;
    out[idx] = 0.5f * (r0 + r1);
}

// ---------------------------------------------------------------------------
extern "C" void kernel_launch(void* const* d_in, const int* in_sizes, int n_in,
                              void* d_out, int out_size, void* d_ws, size_t ws_size,
                              hipStream_t stream) {
    const float* feat = (const float*)d_in[0];
    const int*   adj  = (const int*)d_in[1];
    const float* W    = (const float*)d_in[2];
    const float* asrc = (const float*)d_in[3];
    const float* adst = (const float*)d_in[4];
    float* out = (float*)d_out;

    // jsplit=4 (40MB ws): grid (64,4) = 256 blocks = exactly 1/CU, zero tail
    const int jsplit = (ws_size >= ((size_t)40 << 20)) ? 4 : 2;
    const int jchunk = NN / jsplit;

    char* ws = (char*)d_ws;
    unsigned short* Tt = (unsigned short*)ws;                       // 4 MB
    float* s    = (float*)(ws + ((size_t)4 << 20));                 // 64 KB
    float* dsc  = (float*)(ws + ((size_t)4 << 20) + (64 << 10));    // 64 KB
    float* den  = (float*)(ws + ((size_t)4 << 20) + (128 << 10));   // <=256 KB
    float* nump = (float*)(ws + ((size_t)8 << 20));                 // jsplit*8 MB

    k_transform<<<256, 256, 0, stream>>>(feat, W, asrc, adst, Tt, s, dsc);
    k_gat<<<dim3(NN / BI, jsplit), 1024, 0, stream>>>(adj, Tt, s, dsc, nump, den, jchunk);
    k_combine<<<NN * FD / 256, 256, 0, stream>>>(nump, den, out, jsplit);
}